// Round 7
// baseline (376.607 us; speedup 1.0000x reference)
//
#include <hip/hip_runtime.h>
#include <hip/hip_bf16.h>

#define D 64
#define FP_SCALE 262144.0f          // 2^18 (order-free int accumulation)
#define FP_INV   (1.0f / 262144.0f)

__device__ __forceinline__ unsigned short f2bf(float f) {   // rtne f32->bf16
    unsigned int u = __float_as_uint(f);
    u += 0x7fffu + ((u >> 16) & 1u);
    return (unsigned short)(u >> 16);
}

// ---------- CSR build ----------
__global__ void hist_kernel(const int* __restrict__ dst, int* __restrict__ counts, int E) {
    int e = blockIdx.x * blockDim.x + threadIdx.x;
    if (e < E) atomicAdd(&counts[dst[e]], 1);
}

// Wave-scan allocator: inclusive __shfl_up scan + ONE atomic per wave.
__global__ void alloc_kernel(int* __restrict__ counts_cursor, int2* __restrict__ seg,
                             int* __restrict__ total, int N) {
    int n = blockIdx.x * blockDim.x + threadIdx.x;
    int lane = threadIdx.x & 63;
    int c = (n < N) ? counts_cursor[n] : 0;
    int incl = c;
    #pragma unroll
    for (int off = 1; off < 64; off <<= 1) {
        int t = __shfl_up(incl, off);
        if (lane >= off) incl += t;
    }
    int wsum = __shfl(incl, 63);
    int base = 0;
    if (lane == 63) base = atomicAdd(total, wsum);
    base = __shfl(base, 63);
    if (n < N) {
        int st = base + incl - c;
        seg[n] = make_int2(st, c);
        counts_cursor[n] = st;      // becomes cursor for fill
    }
}

// Placement within a segment is atomic-order nondeterministic, but the
// gather's integer accumulation is order-free, so the sum is input-pure.
__global__ void fill_kernel(const int* __restrict__ src, const int* __restrict__ dst,
                            const float* __restrict__ ew, int* __restrict__ cursor,
                            float2* __restrict__ perm, int E) {
    int e = blockIdx.x * blockDim.x + threadIdx.x;
    if (e < E) {
        int p = atomicAdd(&cursor[dst[e]], 1);
        perm[p] = make_float2(__int_as_float(src[e]), ew[e] * FP_SCALE);
    }
}

// f32 -> bf16 convert (for iteration 0 input)
__global__ void cvt_kernel(const float* __restrict__ in, unsigned short* __restrict__ out, int n4) {
    int i = blockIdx.x * blockDim.x + threadIdx.x;
    if (i >= n4) return;
    float4 v = reinterpret_cast<const float4*>(in)[i];
    ushort4 o;
    o.x = f2bf(v.x); o.y = f2bf(v.y); o.z = f2bf(v.z); o.w = f2bf(v.w);
    reinterpret_cast<ushort4*>(out)[i] = o;
}

// ---------- fused aggregate + linear + relu ----------
// One wave per node. 4 lane-groups of 16 stream edges (bf16 rows: 16 lanes x
// 8B = 128B row), unrolled x4 -> 16 rows in flight. int32 fixed-point
// accumulation keeps the node sum independent of CSR arrival order ->
// bit-deterministic across graph replays, no sort.
// Epilogue: W[lane][*] hoisted to 16xfloat4 VGPRs per wave; agg row broadcast
// via per-wave LDS slice (b128 write + 16 same-address b128 reads), 64 fma in
// 4 independent chains. No readlane, no W LDS traffic, no __syncthreads.
#define EDGE_ACC(m)                                                        \
    {                                                                      \
        int s_ = __float_as_int((m).x);                                    \
        float w_ = (m).y;                                                  \
        uint2 u_ = *reinterpret_cast<const uint2*>(&xb[(size_t)s_ * D + c]); \
        ix += (int)(w_ * __uint_as_float(u_.x << 16));                     \
        iy += (int)(w_ * __uint_as_float(u_.x & 0xffff0000u));             \
        iz += (int)(w_ * __uint_as_float(u_.y << 16));                     \
        iw += (int)(w_ * __uint_as_float(u_.y & 0xffff0000u));             \
    }

template<bool OUT_BF>
__global__ void gather_linear_kernel(const unsigned short* __restrict__ xb,
                                     const float2* __restrict__ perm,
                                     const int2* __restrict__ seg,
                                     const float* __restrict__ W,
                                     const float* __restrict__ bias,
                                     void* __restrict__ xout, int N) {
    __shared__ float aggRow[4][D];             // per-wave broadcast slice
    int t = threadIdx.x;                       // 256 threads = 4 waves
    int wave = t >> 6;
    int lane = t & 63;

    // hoist this lane's W row + bias into registers (reused for ~6 nodes/wave)
    float4 wreg[16];
    #pragma unroll
    for (int q = 0; q < 16; ++q)
        wreg[q] = *reinterpret_cast<const float4*>(&W[(size_t)lane * D + 4 * q]);
    float blane = bias[lane];

    int g = lane >> 4;            // edge sub-stream 0..3
    int c = (lane & 15) << 2;     // feature quad base (elements)
    int nwaves = gridDim.x * 4;
    for (int n = blockIdx.x * 4 + wave; n < N; n += nwaves) {
        int2 sc = seg[n];
        int st = sc.x, cnt = sc.y;
        int ix = 0, iy = 0, iz = 0, iw = 0;
        int k = g;
        for (; k + 12 < cnt; k += 16) {        // unroll x4: 16 rows in flight/wave
            float2 m0 = perm[st + k];
            float2 m1 = perm[st + k + 4];
            float2 m2 = perm[st + k + 8];
            float2 m3 = perm[st + k + 12];
            EDGE_ACC(m0); EDGE_ACC(m1); EDGE_ACC(m2); EDGE_ACC(m3);
        }
        for (; k < cnt; k += 4) {              // remainder (<=3 per group)
            float2 m0 = perm[st + k];
            EDGE_ACC(m0);
        }
        // integer butterfly across the 4 groups (order-free)
        #pragma unroll
        for (int mask = 16; mask <= 32; mask <<= 1) {
            ix += __shfl_xor(ix, mask);
            iy += __shfl_xor(iy, mask);
            iz += __shfl_xor(iz, mask);
            iw += __shfl_xor(iw, mask);
        }
        // group 0 publishes the agg row; same-wave LDS write->read needs no
        // barrier (per-wave DS ops are in order; compiler emits lgkmcnt).
        if (g == 0) {
            *reinterpret_cast<float4*>(&aggRow[wave][c]) =
                make_float4((float)ix * FP_INV, (float)iy * FP_INV,
                            (float)iz * FP_INV, (float)iw * FP_INV);
        }
        float o0 = 0.f, o1 = 0.f, o2 = 0.f, o3 = 0.f;
        #pragma unroll
        for (int q = 0; q < 16; ++q) {
            float4 a = *reinterpret_cast<const float4*>(&aggRow[wave][4 * q]); // broadcast
            o0 = fmaf(a.x, wreg[q].x, o0);
            o1 = fmaf(a.y, wreg[q].y, o1);
            o2 = fmaf(a.z, wreg[q].z, o2);
            o3 = fmaf(a.w, wreg[q].w, o3);
        }
        float o = fmaxf(blane + ((o0 + o1) + (o2 + o3)), 0.0f);
        if (OUT_BF) ((unsigned short*)xout)[(size_t)n * D + lane] = f2bf(o);
        else        ((float*)xout)[(size_t)n * D + lane] = o;
    }
}

// ---------- fallback (int-atomic path, deterministic, f32) if ws too small ----------
__global__ void rpi_scatter_kernel(const float* __restrict__ x,
                                   const int* __restrict__ src,
                                   const int* __restrict__ dst,
                                   const float* __restrict__ ew,
                                   int* __restrict__ agg, int E) {
    int tid = blockIdx.x * blockDim.x + threadIdx.x;
    int e = tid >> 4;
    if (e >= E) return;
    int c = (tid & 15) << 2;
    int s = src[e], d = dst[e];
    float w = ew[e] * FP_SCALE;
    float4 v = *reinterpret_cast<const float4*>(&x[(size_t)s * D + c]);
    int* o = &agg[(size_t)d * D + c];
    atomicAdd(o + 0, (int)(w * v.x));
    atomicAdd(o + 1, (int)(w * v.y));
    atomicAdd(o + 2, (int)(w * v.z));
    atomicAdd(o + 3, (int)(w * v.w));
}

__global__ void rpi_linear_relu_kernel(const int* __restrict__ agg,
                                       const float* __restrict__ W,
                                       const float* __restrict__ b,
                                       float* __restrict__ out, int N) {
    __shared__ float Ws[D][D + 1];
    __shared__ float bs[D];
    int t = threadIdx.x;
    for (int i = t; i < D * D; i += 256) Ws[i >> 6][i & 63] = W[i];
    if (t < D) bs[t] = b[t];
    __syncthreads();
    int wave = t >> 6, lane = t & 63;
    int nwaves = gridDim.x * 4;
    for (int n = blockIdx.x * 4 + wave; n < N; n += nwaves) {
        const int* arow = &agg[(size_t)n * D];
        float acc = bs[lane];
        #pragma unroll
        for (int d = 0; d < D; ++d) acc = fmaf((float)arow[d] * FP_INV, Ws[lane][d], acc);
        out[(size_t)n * D + lane] = fmaxf(acc, 0.0f);
    }
}

extern "C" void kernel_launch(void* const* d_in, const int* in_sizes, int n_in,
                              void* d_out, int out_size, void* d_ws, size_t ws_size,
                              hipStream_t stream) {
    const float* x0 = (const float*)d_in[0];   // [N, 64]
    const int*   ei = (const int*)d_in[1];     // [2, E]
    const float* ew = (const float*)d_in[2];   // [E]
    const float* W  = (const float*)d_in[3];   // [64, 64]
    const float* b  = (const float*)d_in[4];   // [64]
    float* out = (float*)d_out;                // [N, 64]

    int N = in_sizes[0] / D;
    int E = in_sizes[2];
    const int* src = ei;
    const int* dst = ei + E;

    size_t xeb      = (size_t)N * D * sizeof(unsigned short);  // bf16 x buffer
    size_t intBytes = ((size_t)3 * N + 4) * sizeof(int);       // seg(2N) + cursor(N) + total
    size_t need     = 2 * xeb + intBytes + (size_t)E * sizeof(float2);

    if (ws_size >= need) {
        unsigned short* xb1 = (unsigned short*)d_ws;
        unsigned short* xb2 = xb1 + (size_t)N * D;
        int2*  seg    = (int2*)((char*)d_ws + 2 * xeb);
        int*   cursor = (int*)(seg + N);
        int*   total  = cursor + N;
        float2* perm  = (float2*)((char*)d_ws + 2 * xeb + intBytes);

        hipMemsetAsync(cursor, 0, (size_t)(N + 2) * sizeof(int), stream);  // cursor + total
        int eb = (E + 255) / 256;
        int nb = (N + 255) / 256;
        int n4 = N * D / 4;
        hist_kernel <<<eb, 256, 0, stream>>>(dst, cursor, E);
        alloc_kernel<<<nb, 256, 0, stream>>>(cursor, seg, total, N);
        fill_kernel <<<eb, 256, 0, stream>>>(src, dst, ew, cursor, perm, E);
        cvt_kernel  <<<(n4 + 255) / 256, 256, 0, stream>>>(x0, xb1, n4);

        gather_linear_kernel<true> <<<4096, 256, 0, stream>>>(xb1, perm, seg, W, b, xb2, N);
        gather_linear_kernel<true> <<<4096, 256, 0, stream>>>(xb2, perm, seg, W, b, xb1, N);
        gather_linear_kernel<false><<<4096, 256, 0, stream>>>(xb1, perm, seg, W, b, out, N);
    } else {
        int* agg = (int*)d_ws;
        const float* xcur = x0;
        int sb = (E * 16 + 255) / 256;
        for (int it = 0; it < 3; ++it) {
            hipMemsetAsync(agg, 0, (size_t)N * D * sizeof(int), stream);
            rpi_scatter_kernel<<<sb, 256, 0, stream>>>(xcur, src, dst, ew, agg, E);
            rpi_linear_relu_kernel<<<2048, 256, 0, stream>>>(agg, W, b, out, N);
            xcur = out;
        }
    }
}